// Round 7
// baseline (432.429 us; speedup 1.0000x reference)
//
#include <hip/hip_runtime.h>
#include <hip/hip_bf16.h>
#include <math.h>

typedef unsigned short u16;
typedef __attribute__((ext_vector_type(8))) __bf16 bf16x8;
typedef __attribute__((ext_vector_type(4))) float floatx4;

#define SEQ   4096
#define BATCH 8
#define ROWS  32768   // BATCH*SEQ
#define C     512
#define NH    16
#define HD    32

__device__ inline u16 f2bf(float f) {
    union { float f; unsigned u; } v; v.f = f;
    unsigned r = (v.u + 0x7FFFu + ((v.u >> 16) & 1u)) >> 16;
    return (u16)r;
}
__device__ inline float bf2f(u16 h) {
    union { unsigned u; float f; } v; v.u = ((unsigned)h) << 16;
    return v.f;
}

// async global -> LDS, 16B per lane; lds ptr must be wave-uniform (HW adds lane*16)
__device__ inline void g2lds16(const u16* g, u16* l) {
    __builtin_amdgcn_global_load_lds((const __attribute__((address_space(1))) unsigned*)g,
                                     (__attribute__((address_space(3))) unsigned*)l, 16, 0, 0);
}

// ---------------- weight prep: fp32 (k,n) -> bf16 transposed (n,k), 64x64 LDS tiles ----------------
__global__ __launch_bounds__(256) void prep_weights(
    const float* __restrict__ Wq, const float* __restrict__ Wk,
    const float* __restrict__ Wv, const float* __restrict__ Wm,
    const float* __restrict__ W1, const float* __restrict__ W2,
    u16* __restrict__ Wqkvt, u16* __restrict__ Wmt,
    u16* __restrict__ W1t, u16* __restrict__ W2t)
{
    int blk = blockIdx.x;                 // 6 mats * 64 tiles
    int mat = blk >> 6;
    int tile = blk & 63;
    int k0 = (tile >> 3) * 64, n0 = (tile & 7) * 64;
    const float* src; u16* dst;
    switch (mat) {
        case 0: src = Wq; dst = Wqkvt;              break;
        case 1: src = Wk; dst = Wqkvt + 512*512;    break;
        case 2: src = Wv; dst = Wqkvt + 2*512*512;  break;
        case 3: src = Wm; dst = Wmt;                break;
        case 4: src = W1; dst = W1t;                break;
        default: src = W2; dst = W2t;               break;
    }
    __shared__ float ts[64][65];
    int t = threadIdx.x;
    #pragma unroll
    for (int i = 0; i < 16; i++) {
        int e = i * 256 + t;
        int kr = e >> 6, nc = e & 63;
        ts[kr][nc] = src[(size_t)(k0 + kr) * 512 + n0 + nc];   // coalesced 256B rows
    }
    __syncthreads();
    #pragma unroll
    for (int i = 0; i < 2; i++) {
        int e = i * 256 + t;                 // 512 chunks of 8
        int nr = e >> 3, kc0 = (e & 7) * 8;
        union { uint4 v; u16 u[8]; } o;
        #pragma unroll
        for (int q = 0; q < 8; q++) o.u[q] = f2bf(ts[kc0 + q][nr]);
        *(uint4*)(dst + (size_t)(n0 + nr) * 512 + k0 + kc0) = o.v;   // coalesced 16B stores
    }
}

// ---------------- layernorm: fp32 in -> bf16 out, one wave per row ----------------
__global__ __launch_bounds__(256) void ln_kernel(
    const float* __restrict__ in, const float* __restrict__ g,
    const float* __restrict__ b, u16* __restrict__ out)
{
    int row  = blockIdx.x * 4 + (threadIdx.x >> 6);
    int lane = threadIdx.x & 63;
    const float* p = in + (size_t)row * C + lane * 8;
    float4 v0 = *(const float4*)p;
    float4 v1 = *(const float4*)(p + 4);
    float s  = v0.x + v0.y + v0.z + v0.w + v1.x + v1.y + v1.z + v1.w;
    float s2 = v0.x*v0.x + v0.y*v0.y + v0.z*v0.z + v0.w*v0.w
             + v1.x*v1.x + v1.y*v1.y + v1.z*v1.z + v1.w*v1.w;
    #pragma unroll
    for (int off = 1; off < 64; off <<= 1) {
        s  += __shfl_xor(s, off);
        s2 += __shfl_xor(s2, off);
    }
    float mean = s * (1.f / C);
    float var  = s2 * (1.f / C) - mean * mean;
    float inv  = rsqrtf(var + 1e-6f);
    int c = lane * 8;
    float4 g0 = *(const float4*)(g + c), g1 = *(const float4*)(g + c + 4);
    float4 b0 = *(const float4*)(b + c), b1 = *(const float4*)(b + c + 4);
    union { uint4 v; u16 u[8]; } o;
    o.u[0] = f2bf((v0.x - mean) * inv * g0.x + b0.x);
    o.u[1] = f2bf((v0.y - mean) * inv * g0.y + b0.y);
    o.u[2] = f2bf((v0.z - mean) * inv * g0.z + b0.z);
    o.u[3] = f2bf((v0.w - mean) * inv * g0.w + b0.w);
    o.u[4] = f2bf((v1.x - mean) * inv * g1.x + b1.x);
    o.u[5] = f2bf((v1.y - mean) * inv * g1.y + b1.y);
    o.u[6] = f2bf((v1.z - mean) * inv * g1.z + b1.z);
    o.u[7] = f2bf((v1.w - mean) * inv * g1.w + b1.w);
    *(uint4*)(out + (size_t)row * C + c) = o.v;
}

// ---------------- bf16 MFMA GEMM, 128x128 tile (proven structure, grouped XCD swizzle) ----------
template <int EPI>
__global__ __launch_bounds__(256, 2) void gemm_tile(
    const u16* __restrict__ A, const u16* __restrict__ Bt,
    int K, int ldc, int nx, int ypx,
    u16* __restrict__ outb, float* __restrict__ outf,
    const float* __restrict__ bias, const float* __restrict__ resid)
{
    __shared__ u16 lsA[128 * 64];
    __shared__ u16 lsB[128 * 64];
    const int t = threadIdx.x;
    const int w = t >> 6, l = t & 63, lr = l & 15, quad = l >> 4;
    // grouped XCD swizzle: 2 y-tiles per group, x-major inside the group
    const int g = blockIdx.x;
    const int xcd = g & 7;
    const int q = g >> 3;
    const int npg = nx * 2;
    const int grp = q / npg, rem = q - grp * npg;
    const int tx = rem >> 1;
    const int ty = xcd * ypx + grp * 2 + (rem & 1);
    const int m0 = ty * 128, n0 = tx * 128;
    const int RW = (w >> 1) * 64, CW = (w & 1) * 64;

    floatx4 acc[4][4];
    #pragma unroll
    for (int i = 0; i < 4; i++)
        #pragma unroll
        for (int j = 0; j < 4; j++) { floatx4 z = {0.f, 0.f, 0.f, 0.f}; acc[i][j] = z; }

    const int srow = w * 32 + (l >> 3);
    const int scol = (((l & 7) - (l >> 3)) & 7) * 8;      // row&7 == l>>3 here
    const u16* Ag = A  + (size_t)(m0 + srow) * K + scol;
    const u16* Bg = Bt + (size_t)(n0 + srow) * K + scol;
    u16* lAw = lsA + w * 2048;
    u16* lBw = lsB + w * 2048;

    for (int kk = 0; kk < K; kk += 64) {
        __syncthreads();
        #pragma unroll
        for (int c = 0; c < 4; c++) {
            g2lds16(Ag + (size_t)(c * 8) * K + kk, lAw + c * 512);
            g2lds16(Bg + (size_t)(c * 8) * K + kk, lBw + c * 512);
        }
        __syncthreads();
        #pragma unroll
        for (int ks = 0; ks < 2; ks++) {
            bf16x8 af[4], bfr[4];
            const int m = ((ks * 4 + quad + (lr & 7)) & 7) * 8;
            #pragma unroll
            for (int i = 0; i < 4; i++) {
                af[i]  = *(const bf16x8*)(lsA + (RW + i * 16 + lr) * 64 + m);
                bfr[i] = *(const bf16x8*)(lsB + (CW + i * 16 + lr) * 64 + m);
            }
            #pragma unroll
            for (int i = 0; i < 4; i++)
                #pragma unroll
                for (int j = 0; j < 4; j++)
                    acc[i][j] = __builtin_amdgcn_mfma_f32_16x16x32_bf16(af[i], bfr[j], acc[i][j], 0, 0, 0);
        }
    }

    #pragma unroll
    for (int i = 0; i < 4; i++) {
        #pragma unroll
        for (int j = 0; j < 4; j++) {
            #pragma unroll
            for (int r = 0; r < 4; r++) {
                int row = m0 + RW + i * 16 + quad * 4 + r;
                int col = n0 + CW + j * 16 + lr;
                float v = acc[i][j][r];
                size_t idx = (size_t)row * ldc + col;
                if constexpr (EPI == 0) {
                    if (col < 1024) v = v > 0.f ? v + 1.f : __expf(v);
                    else            v *= (1.0f / SEQ);
                    outb[idx] = f2bf(v);
                } else if constexpr (EPI == 1) {
                    outf[idx] = resid[idx] + v;
                } else if constexpr (EPI == 2) {
                    v += bias[col];
                    v = 0.5f * v * (1.f + erff(v * 0.70710678118f));
                    outb[idx] = f2bf(v);
                } else {
                    outf[idx] = outf[idx] + v + bias[col];
                }
            }
        }
    }
}

// ======== fused x2 = x + msg@Wm, then LN(x2) -> h2, full-row 64x512 tile ========
// 512 thr = 8 waves (2 row-groups x 4 col-groups). B panel streamed in K-chunks of 64
// (A 8KB + B 64KB + stats 2.5KB = 74.5KB LDS, 2 blocks/CU). Same 2-barrier loop and
// staging rotation as gemm_tile (row*128B == 0 mod 32 banks -> same 2-way-free pattern).
// Epilogue: write x2 fp32, row-reduce sum/sumsq (shfl over lr -> LDS partials[64][4]),
// LN stats, normalize from registers, write h2 bf16. Kills the separate LN2 pass (96MB).
__global__ __launch_bounds__(512, 4) void gemm_wmln(
    const u16* __restrict__ A, const u16* __restrict__ Bt,
    const float* __restrict__ resid, const float* __restrict__ gf,
    const float* __restrict__ bf, float* __restrict__ out,
    u16* __restrict__ h2)
{
    __shared__ u16 lsA[64 * 64];      // 8 KB
    __shared__ u16 lsB[512 * 64];     // 64 KB
    __shared__ float ps[64][4][2];    // per-row partial sums per col-group
    __shared__ float stats[64][2];    // mean, inv

    const int t = threadIdx.x;
    const int w = t >> 6, l = t & 63, lr = l & 15, quad = l >> 4;
    const int wr = w >> 2, wc = w & 3;
    const int m0 = blockIdx.x * 64;

    // staging (gemm_tile rotation): lane l -> row l>>3 of an 8-row group, phys chunk l&7
    const int srow = l >> 3;
    const int scol = (((l & 7) - srow) & 7) * 8;
    const u16* Ag = A  + (size_t)(m0 + w * 8 + srow) * 512 + scol;
    const u16* Bg = Bt + (size_t)(w * 64 + srow) * 512 + scol;
    u16* lAw = lsA + w * 512;
    u16* lBw = lsB + w * 4096;

    floatx4 acc[2][8];
    #pragma unroll
    for (int i = 0; i < 2; i++)
        #pragma unroll
        for (int j = 0; j < 8; j++) { floatx4 z = {0.f, 0.f, 0.f, 0.f}; acc[i][j] = z; }

    for (int kk = 0; kk < 512; kk += 64) {
        __syncthreads();
        g2lds16(Ag + kk, lAw);
        #pragma unroll
        for (int c = 0; c < 8; c++)
            g2lds16(Bg + (size_t)(c * 8) * 512 + kk, lBw + c * 512);
        __syncthreads();
        #pragma unroll
        for (int ks = 0; ks < 2; ks++) {
            bf16x8 af[2], bfr[8];
            const int m = ((ks * 4 + quad + (lr & 7)) & 7) * 8;
            af[0] = *(const bf16x8*)(lsA + (wr * 32 + lr) * 64 + m);
            af[1] = *(const bf16x8*)(lsA + (wr * 32 + 16 + lr) * 64 + m);
            #pragma unroll
            for (int j = 0; j < 8; j++)
                bfr[j] = *(const bf16x8*)(lsB + (wc * 128 + j * 16 + lr) * 64 + m);
            #pragma unroll
            for (int i = 0; i < 2; i++)
                #pragma unroll
                for (int j = 0; j < 8; j++)
                    acc[i][j] = __builtin_amdgcn_mfma_f32_16x16x32_bf16(af[i], bfr[j], acc[i][j], 0, 0, 0);
        }
    }

    // ---- pass 1: x2 = resid + v; write out; accumulate row sums ----
    float s[2][4], s2[2][4];
    #pragma unroll
    for (int i = 0; i < 2; i++)
        #pragma unroll
        for (int r = 0; r < 4; r++) { s[i][r] = 0.f; s2[i][r] = 0.f; }
    #pragma unroll
    for (int i = 0; i < 2; i++) {
        #pragma unroll
        for (int j = 0; j < 8; j++) {
            #pragma unroll
            for (int r = 0; r < 4; r++) {
                int row = m0 + wr * 32 + i * 16 + quad * 4 + r;
                int col = wc * 128 + j * 16 + lr;
                size_t idx = (size_t)row * 512 + col;
                float x2 = resid[idx] + acc[i][j][r];
                out[idx] = x2;
                acc[i][j][r] = x2;            // keep for LN pass
                s[i][r]  += x2;
                s2[i][r] += x2 * x2;
            }
        }
    }
    #pragma unroll
    for (int i = 0; i < 2; i++)
        #pragma unroll
        for (int r = 0; r < 4; r++) {
            #pragma unroll
            for (int off = 1; off < 16; off <<= 1) {
                s[i][r]  += __shfl_xor(s[i][r], off);
                s2[i][r] += __shfl_xor(s2[i][r], off);
            }
        }
    if (lr == 0) {
        #pragma unroll
        for (int i = 0; i < 2; i++)
            #pragma unroll
            for (int r = 0; r < 4; r++) {
                int rl = wr * 32 + i * 16 + quad * 4 + r;
                ps[rl][wc][0] = s[i][r];
                ps[rl][wc][1] = s2[i][r];
            }
    }
    __syncthreads();
    if (t < 64) {
        float ssum = ps[t][0][0] + ps[t][1][0] + ps[t][2][0] + ps[t][3][0];
        float ssq  = ps[t][0][1] + ps[t][1][1] + ps[t][2][1] + ps[t][3][1];
        float mean = ssum * (1.f / C);
        float var  = ssq * (1.f / C) - mean * mean;
        stats[t][0] = mean;
        stats[t][1] = rsqrtf(var + 1e-6f);
    }
    __syncthreads();
    // ---- pass 2: normalize from registers, write h2 bf16 ----
    float gv[8], bv[8];
    #pragma unroll
    for (int j = 0; j < 8; j++) {
        int col = wc * 128 + j * 16 + lr;
        gv[j] = gf[col];
        bv[j] = bf[col];
    }
    #pragma unroll
    for (int i = 0; i < 2; i++) {
        #pragma unroll
        for (int r = 0; r < 4; r++) {
            int rl = wr * 32 + i * 16 + quad * 4 + r;
            float mean = stats[rl][0], inv = stats[rl][1];
            #pragma unroll
            for (int j = 0; j < 8; j++) {
                int col = wc * 128 + j * 16 + lr;
                float h = (acc[i][j][r] - mean) * inv * gv[j] + bv[j];
                h2[(size_t)(m0 + rl) * 512 + col] = f2bf(h);
            }
        }
    }
}

// ---------------- KV partials via MFMA: per-wave private LDS tiles, no atomics ----------------
__global__ __launch_bounds__(256) void kv_reduce(
    const u16* __restrict__ qkv, float* __restrict__ Pkv, float* __restrict__ PKsum)
{
    const int bh = blockIdx.x;            // 0..127
    const int b = bh >> 4, h = bh & 15;
    const int chunk = blockIdx.y;         // 0..7
    const int t = threadIdx.x;
    const int w = t >> 6, l = t & 63, lr = l & 15, quad = l >> 4;
    __shared__ u16 lds[4 * 2 * 2048];     // [wave][buf][K 1024 | V 1024] = 32 KB

    const int sbase = chunk * 512 + w * 128;
    const u16* qbase = qkv + (size_t)b * SEQ * 1536 + 512 + h * HD;  // K part; V = +512

    const int sl0 = l >> 2;               // rows 0..15 (instr 0)
    const int sl1 = 16 + sl0;             // rows 16..31 (instr 1)
    const int cl  = l & 3;
    const int cg0 = (cl + (sl0 >> 3)) & 3;
    const int cg1 = (cl + (sl1 >> 3)) & 3;
    const int gof0 = sl0 * 1536 + cg0 * 8;
    const int gof1 = sl1 * 1536 + cg1 * 8;

    u16* myl = lds + w * 4096;

    const int offA0 = quad * 256 + ((((lr >> 3) + 0) - quad) & 3) * 8 + (lr & 7);  // d 0..15
    const int offA1 = quad * 256 + ((((lr >> 3) + 2) - quad) & 3) * 8 + (lr & 7);  // d 16..31

    floatx4 a00 = {0,0,0,0}, a01 = {0,0,0,0}, a10 = {0,0,0,0}, a11 = {0,0,0,0};
    float ks0 = 0.f, ks1 = 0.f;

    {
        const u16* gK = qbase + (size_t)sbase * 1536;
        g2lds16(gK + gof0,       myl);
        g2lds16(gK + gof1,       myl + 512);
        g2lds16(gK + 512 + gof0, myl + 1024);
        g2lds16(gK + 512 + gof1, myl + 1536);
    }
    #pragma unroll
    for (int st = 0; st < 4; st++) {
        if (st < 3) {                      // prefetch next buf before the drain
            const u16* gK = qbase + (size_t)(sbase + (st + 1) * 32) * 1536;
            u16* nl = myl + ((st + 1) & 1) * 2048;
            g2lds16(gK + gof0,       nl);
            g2lds16(gK + gof1,       nl + 512);
            g2lds16(gK + 512 + gof0, nl + 1024);
            g2lds16(gK + 512 + gof1, nl + 1536);
        }
        __syncthreads();                   // vmcnt(0) drain, compiler-safe fence
        const u16* lK = myl + (st & 1) * 2048;
        const u16* lV = lK + 1024;
        union { bf16x8 v; u16 u[8]; } fa0, fa1, fb0, fb1;
        #pragma unroll
        for (int j = 0; j < 8; j++) {
            fa0.u[j] = lK[offA0 + j * 32];
            fa1.u[j] = lK[offA1 + j * 32];
            fb0.u[j] = lV[offA0 + j * 32];
            fb1.u[j] = lV[offA1 + j * 32];
        }
        #pragma unroll
        for (int j = 0; j < 8; j++) { ks0 += bf2f(fa0.u[j]); ks1 += bf2f(fa1.u[j]); }
        a00 = __builtin_amdgcn_mfma_f32_16x16x32_bf16(fa0.v, fb0.v, a00, 0, 0, 0);
        a01 = __builtin_amdgcn_mfma_f32_16x16x32_bf16(fa0.v, fb1.v, a01, 0, 0, 0);
        a10 = __builtin_amdgcn_mfma_f32_16x16x32_bf16(fa1.v, fb0.v, a10, 0, 0, 0);
        a11 = __builtin_amdgcn_mfma_f32_16x16x32_bf16(fa1.v, fb1.v, a11, 0, 0, 0);
    }

    const int p = bh * 32 + chunk * 4 + w;
    float* dst = Pkv + (size_t)p * 1024;
    floatx4 accs[2][2] = {{a00, a01}, {a10, a11}};
    #pragma unroll
    for (int i = 0; i < 2; i++)
        #pragma unroll
        for (int j = 0; j < 2; j++)
            #pragma unroll
            for (int r = 0; r < 4; r++)
                dst[(i * 16 + quad * 4 + r) * 32 + j * 16 + lr] = accs[i][j][r];

    float k0 = ks0 + __shfl_xor(ks0, 16); k0 += __shfl_xor(k0, 32);
    float k1 = ks1 + __shfl_xor(ks1, 16); k1 += __shfl_xor(k1, 32);
    if (quad == 0) {
        PKsum[p * 32 + lr]      = k0;
        PKsum[p * 32 + 16 + lr] = k1;
    }
}

// ---------------- final reduce: 512 blocks (128 bh x 4 parts) ----------------
__global__ __launch_bounds__(256) void kv_final(
    const float* __restrict__ Pkv, const float* __restrict__ PKsum,
    float* __restrict__ KV, float* __restrict__ Ksum)
{
    const int blk = blockIdx.x;          // 512 = 128 bh x 4 parts
    const int bh = blk >> 2, part = blk & 3;
    const int t = threadIdx.x;
    const float* src = Pkv + (size_t)bh * 32 * 1024 + part * 256 + t;
    float a = 0.f;
    #pragma unroll 4
    for (int p = 0; p < 32; p++) a += src[(size_t)p * 1024];
    KV[(size_t)bh * 1024 + part * 256 + t] = a;
    if (part == 0 && t < 32) {
        float s = 0.f;
        for (int p = 0; p < 32; p++) s += PKsum[(bh * 32 + p) * 32 + t];
        Ksum[bh * 32 + t] = s;
    }
}

// ---------------- msg = (Q . KV) * SEQ / (Q . Ksum + eps) ----------------
__global__ __launch_bounds__(256) void msg_kernel(
    const u16* __restrict__ qkv, const float* __restrict__ KV,
    const float* __restrict__ Ksum, u16* __restrict__ msg)
{
    int blk = blockIdx.x;           // 1024 blocks
    int b = blk >> 7;
    int r0 = (blk & 127) * 32;
    int t = threadIdx.x;
    int h = t >> 4;
    int vd = (t & 15) * 2;
    float kv0[32], kv1[32], ksr[32];
    const float* kvh = KV + ((size_t)b * 16 + h) * 1024;
    const float* ksh = Ksum + (b * 16 + h) * 32;
    #pragma unroll
    for (int d = 0; d < 32; d++) {
        kv0[d] = kvh[d * 32 + vd];
        kv1[d] = kvh[d * 32 + vd + 1];
        ksr[d] = ksh[d];
    }
    __shared__ u16 Qs[4 * 512];
    const int srr = t >> 6;
    const int scc = (t & 63) * 8;
    for (int rg = 0; rg < 32; rg += 4) {
        size_t row = (size_t)b * SEQ + r0 + rg;
        uint4 qv = *(const uint4*)(qkv + (row + srr) * 1536 + scc);
        __syncthreads();
        *(uint4*)(Qs + srr * 512 + scc) = qv;
        __syncthreads();
        #pragma unroll
        for (int r2 = 0; r2 < 4; r2++) {
            const u16* qp = Qs + r2 * 512 + h * HD;
            float q[32];
            #pragma unroll
            for (int i0 = 0; i0 < 32; i0 += 8) {
                union { uint4 v; u16 u[8]; } uu;
                uu.v = *(const uint4*)(qp + i0);
                #pragma unroll
                for (int jq = 0; jq < 8; jq++) q[i0 + jq] = bf2f(uu.u[jq]);
            }
            float zdot = 0.f, m0 = 0.f, m1 = 0.f;
            #pragma unroll
            for (int d = 0; d < 32; d++) {
                float qd = q[d];
                zdot += qd * ksr[d];
                m0   += qd * kv0[d];
                m1   += qd * kv1[d];
            }
            float z = (float)SEQ / (zdot + 1e-6f);
            unsigned pack = (unsigned)f2bf(m0 * z) | ((unsigned)f2bf(m1 * z) << 16);
            *(unsigned*)(msg + (row + r2) * C + h * HD + vd) = pack;
        }
    }
}

extern "C" void kernel_launch(void* const* d_in, const int* in_sizes, int n_in,
                              void* d_out, int out_size, void* d_ws, size_t ws_size,
                              hipStream_t stream) {
    const float* x     = (const float*)d_in[0];
    const float* Wq    = (const float*)d_in[1];
    const float* Wk    = (const float*)d_in[2];
    const float* Wv    = (const float*)d_in[3];
    const float* Wm    = (const float*)d_in[4];
    const float* W1    = (const float*)d_in[5];
    const float* b1    = (const float*)d_in[6];
    const float* W2    = (const float*)d_in[7];
    const float* b2    = (const float*)d_in[8];
    const float* g_att = (const float*)d_in[9];
    const float* b_att = (const float*)d_in[10];
    const float* g_ffn = (const float*)d_in[11];
    const float* b_ffn = (const float*)d_in[12];
    float* out = (float*)d_out;

    // Workspace map (live ranges disjoint in time)
    char* ws = (char*)d_ws;
    u16*   Wqkvt = (u16*)(ws);                    // 1.5 MB
    u16*   Wmt   = (u16*)(ws + 0x180000);         // 0.5 MB
    u16*   W1t   = (u16*)(ws + 0x200000);         // 0.5 MB
    u16*   W2t   = (u16*)(ws + 0x280000);         // 0.5 MB
    float* KV    = (float*)(ws + 0x300000);       // 512 KB
    float* Ksum  = (float*)(ws + 0x380000);       // 16 KB
    u16*   hb    = (u16*)(ws + 0x400000);         // 32 MB (LN1 out; reused as msg)
    float* Pkv   = (float*)(ws + 0x400000);       // 16 MB, aliases hb (hb dead in step 4)
    float* PKsum = (float*)(ws + 0x1400000);      // 512 KB
    u16*   qkv   = (u16*)(ws + 0x2400000);        // 96 MB
    u16*   h2    = qkv;                           // 32 MB (qkv dead after step 5)
    u16*   f1    = (u16*)(ws + 0x4400000);        // 32 MB (in qkv tail, dead by step 8)

    // 1. weights -> bf16 transposed
    prep_weights<<<6 * 64, 256, 0, stream>>>(Wq, Wk, Wv, Wm, W1, W2,
                                             Wqkvt, Wmt, W1t, W2t);
    // 2. LN1
    ln_kernel<<<ROWS / 4, 256, 0, stream>>>(x, g_att, b_att, hb);
    // 3. qkv = h @ [Wq|Wk|Wv]  (proven gemm_tile + grouped swizzle)
    gemm_tile<0><<<3072, 256, 0, stream>>>(hb, Wqkvt, 512, 1536, 12, 32,
                                           qkv, nullptr, nullptr, nullptr);
    // 4. KV/Ksum: MFMA partials + final reduce (no atomics, no memset)
    kv_reduce<<<dim3(128, 8), 256, 0, stream>>>(qkv, Pkv, PKsum);
    kv_final<<<512, 256, 0, stream>>>(Pkv, PKsum, KV, Ksum);
    // 5. msg (overwrites hb region - Pkv already consumed)
    msg_kernel<<<1024, 256, 0, stream>>>(qkv, KV, Ksum, hb);
    // 6+7. fused: x2 = x + msg @ Wm (-> d_out), LN2(x2) -> h2   (LN2 pass eliminated)
    gemm_wmln<<<512, 512, 0, stream>>>(hb, Wmt, x, g_ffn, b_ffn, out, h2);
    // 8. f1 = gelu(h2 @ W1 + b1)
    gemm_tile<2><<<1024, 256, 0, stream>>>(h2, W1t, 512, 512, 4, 32,
                                           f1, nullptr, b1, nullptr);
    // 9. out = x2 + f1 @ W2 + b2   (in place on d_out)
    gemm_tile<3><<<1024, 256, 0, stream>>>(f1, W2t, 512, 512, 4, 32,
                                           nullptr, out, b2, nullptr);
}

// Round 8
// 389.859 us; speedup vs baseline: 1.1092x; 1.1092x over previous
//
#include <hip/hip_runtime.h>
#include <hip/hip_bf16.h>
#include <math.h>

typedef unsigned short u16;
typedef __attribute__((ext_vector_type(8))) __bf16 bf16x8;
typedef __attribute__((ext_vector_type(4))) float floatx4;

#define SEQ   4096
#define BATCH 8
#define ROWS  32768   // BATCH*SEQ
#define C     512
#define NH    16
#define HD    32

__device__ inline u16 f2bf(float f) {
    union { float f; unsigned u; } v; v.f = f;
    unsigned r = (v.u + 0x7FFFu + ((v.u >> 16) & 1u)) >> 16;
    return (u16)r;
}
__device__ inline float bf2f(u16 h) {
    union { unsigned u; float f; } v; v.u = ((unsigned)h) << 16;
    return v.f;
}

// async global -> LDS, 16B per lane; lds ptr must be wave-uniform (HW adds lane*16)
__device__ inline void g2lds16(const u16* g, u16* l) {
    __builtin_amdgcn_global_load_lds((const __attribute__((address_space(1))) unsigned*)g,
                                     (__attribute__((address_space(3))) unsigned*)l, 16, 0, 0);
}

// ---------------- weight prep: fp32 (k,n) -> bf16 transposed (n,k), 64x64 LDS tiles ----------------
__global__ __launch_bounds__(256) void prep_weights(
    const float* __restrict__ Wq, const float* __restrict__ Wk,
    const float* __restrict__ Wv, const float* __restrict__ Wm,
    const float* __restrict__ W1, const float* __restrict__ W2,
    u16* __restrict__ Wqkvt, u16* __restrict__ Wmt,
    u16* __restrict__ W1t, u16* __restrict__ W2t)
{
    int blk = blockIdx.x;                 // 6 mats * 64 tiles
    int mat = blk >> 6;
    int tile = blk & 63;
    int k0 = (tile >> 3) * 64, n0 = (tile & 7) * 64;
    const float* src; u16* dst;
    switch (mat) {
        case 0: src = Wq; dst = Wqkvt;              break;
        case 1: src = Wk; dst = Wqkvt + 512*512;    break;
        case 2: src = Wv; dst = Wqkvt + 2*512*512;  break;
        case 3: src = Wm; dst = Wmt;                break;
        case 4: src = W1; dst = W1t;                break;
        default: src = W2; dst = W2t;               break;
    }
    __shared__ float ts[64][65];
    int t = threadIdx.x;
    #pragma unroll
    for (int i = 0; i < 16; i++) {
        int e = i * 256 + t;
        int kr = e >> 6, nc = e & 63;
        ts[kr][nc] = src[(size_t)(k0 + kr) * 512 + n0 + nc];   // coalesced 256B rows
    }
    __syncthreads();
    #pragma unroll
    for (int i = 0; i < 2; i++) {
        int e = i * 256 + t;                 // 512 chunks of 8
        int nr = e >> 3, kc0 = (e & 7) * 8;
        union { uint4 v; u16 u[8]; } o;
        #pragma unroll
        for (int q = 0; q < 8; q++) o.u[q] = f2bf(ts[kc0 + q][nr]);
        *(uint4*)(dst + (size_t)(n0 + nr) * 512 + k0 + kc0) = o.v;   // coalesced 16B stores
    }
}

// ---------------- layernorm: fp32 in -> bf16 out, one wave per row ----------------
__global__ __launch_bounds__(256) void ln_kernel(
    const float* __restrict__ in, const float* __restrict__ g,
    const float* __restrict__ b, u16* __restrict__ out)
{
    int row  = blockIdx.x * 4 + (threadIdx.x >> 6);
    int lane = threadIdx.x & 63;
    const float* p = in + (size_t)row * C + lane * 8;
    float4 v0 = *(const float4*)p;
    float4 v1 = *(const float4*)(p + 4);
    float s  = v0.x + v0.y + v0.z + v0.w + v1.x + v1.y + v1.z + v1.w;
    float s2 = v0.x*v0.x + v0.y*v0.y + v0.z*v0.z + v0.w*v0.w
             + v1.x*v1.x + v1.y*v1.y + v1.z*v1.z + v1.w*v1.w;
    #pragma unroll
    for (int off = 1; off < 64; off <<= 1) {
        s  += __shfl_xor(s, off);
        s2 += __shfl_xor(s2, off);
    }
    float mean = s * (1.f / C);
    float var  = s2 * (1.f / C) - mean * mean;
    float inv  = rsqrtf(var + 1e-6f);
    int c = lane * 8;
    float4 g0 = *(const float4*)(g + c), g1 = *(const float4*)(g + c + 4);
    float4 b0 = *(const float4*)(b + c), b1 = *(const float4*)(b + c + 4);
    union { uint4 v; u16 u[8]; } o;
    o.u[0] = f2bf((v0.x - mean) * inv * g0.x + b0.x);
    o.u[1] = f2bf((v0.y - mean) * inv * g0.y + b0.y);
    o.u[2] = f2bf((v0.z - mean) * inv * g0.z + b0.z);
    o.u[3] = f2bf((v0.w - mean) * inv * g0.w + b0.w);
    o.u[4] = f2bf((v1.x - mean) * inv * g1.x + b1.x);
    o.u[5] = f2bf((v1.y - mean) * inv * g1.y + b1.y);
    o.u[6] = f2bf((v1.z - mean) * inv * g1.z + b1.z);
    o.u[7] = f2bf((v1.w - mean) * inv * g1.w + b1.w);
    *(uint4*)(out + (size_t)row * C + c) = o.v;
}

// ---------------- bf16 MFMA GEMM, 128x128 tile (qkv: compute-bound, at structural ceiling) -----
template <int EPI>
__global__ __launch_bounds__(256, 2) void gemm_tile(
    const u16* __restrict__ A, const u16* __restrict__ Bt,
    int K, int ldc, int nx, int ypx,
    u16* __restrict__ outb, float* __restrict__ outf,
    const float* __restrict__ bias, const float* __restrict__ resid)
{
    __shared__ u16 lsA[128 * 64];
    __shared__ u16 lsB[128 * 64];
    const int t = threadIdx.x;
    const int w = t >> 6, l = t & 63, lr = l & 15, quad = l >> 4;
    // grouped XCD swizzle: 2 y-tiles per group, x-major inside the group
    const int g = blockIdx.x;
    const int xcd = g & 7;
    const int q = g >> 3;
    const int npg = nx * 2;
    const int grp = q / npg, rem = q - grp * npg;
    const int tx = rem >> 1;
    const int ty = xcd * ypx + grp * 2 + (rem & 1);
    const int m0 = ty * 128, n0 = tx * 128;
    const int RW = (w >> 1) * 64, CW = (w & 1) * 64;

    floatx4 acc[4][4];
    #pragma unroll
    for (int i = 0; i < 4; i++)
        #pragma unroll
        for (int j = 0; j < 4; j++) { floatx4 z = {0.f, 0.f, 0.f, 0.f}; acc[i][j] = z; }

    const int srow = w * 32 + (l >> 3);
    const int scol = (((l & 7) - (l >> 3)) & 7) * 8;      // row&7 == l>>3 here
    const u16* Ag = A  + (size_t)(m0 + srow) * K + scol;
    const u16* Bg = Bt + (size_t)(n0 + srow) * K + scol;
    u16* lAw = lsA + w * 2048;
    u16* lBw = lsB + w * 2048;

    for (int kk = 0; kk < K; kk += 64) {
        __syncthreads();
        #pragma unroll
        for (int c = 0; c < 4; c++) {
            g2lds16(Ag + (size_t)(c * 8) * K + kk, lAw + c * 512);
            g2lds16(Bg + (size_t)(c * 8) * K + kk, lBw + c * 512);
        }
        __syncthreads();
        #pragma unroll
        for (int ks = 0; ks < 2; ks++) {
            bf16x8 af[4], bfr[4];
            const int m = ((ks * 4 + quad + (lr & 7)) & 7) * 8;
            #pragma unroll
            for (int i = 0; i < 4; i++) {
                af[i]  = *(const bf16x8*)(lsA + (RW + i * 16 + lr) * 64 + m);
                bfr[i] = *(const bf16x8*)(lsB + (CW + i * 16 + lr) * 64 + m);
            }
            #pragma unroll
            for (int i = 0; i < 4; i++)
                #pragma unroll
                for (int j = 0; j < 4; j++)
                    acc[i][j] = __builtin_amdgcn_mfma_f32_16x16x32_bf16(af[i], bfr[j], acc[i][j], 0, 0, 0);
        }
    }

    #pragma unroll
    for (int i = 0; i < 4; i++) {
        #pragma unroll
        for (int j = 0; j < 4; j++) {
            #pragma unroll
            for (int r = 0; r < 4; r++) {
                int row = m0 + RW + i * 16 + quad * 4 + r;
                int col = n0 + CW + j * 16 + lr;
                float v = acc[i][j][r];
                size_t idx = (size_t)row * ldc + col;
                if constexpr (EPI == 0) {
                    if (col < 1024) v = v > 0.f ? v + 1.f : __expf(v);
                    else            v *= (1.0f / SEQ);
                    outb[idx] = f2bf(v);
                } else if constexpr (EPI == 1) {
                    outf[idx] = resid[idx] + v;
                } else if constexpr (EPI == 2) {
                    v += bias[col];
                    v = 0.5f * v * (1.f + erff(v * 0.70710678118f));
                    outb[idx] = f2bf(v);
                } else {
                    outf[idx] = outf[idx] + v + bias[col];
                }
            }
        }
    }
}

// ---------------- gemm_thin: 64x128 tile, 4 waves -- occupancy-optimized for the memory-bound
// tail GEMMs (Wm/W1/W2: 17 GF vs 64-160 MB traffic; latency-bound at 128^2's 16 waves/CU).
// acc = 2x4 fragments (32 AGPR) + ~60 VGPR -> 5 waves/SIMD by regs; LDS 24 KB -> 6 blocks/CU;
// grid 2048 = 8 blocks/CU available -> ~2.5x the independent blocks to overlap per-K-step
// DMA drains. Staging rotation / read math identical to gemm_tile (proven 0 bank conflicts).
template <int EPI>
__global__ __launch_bounds__(256, 4) void gemm_thin(
    const u16* __restrict__ A, const u16* __restrict__ Bt,
    int ldc, int ypx,
    u16* __restrict__ outb, float* __restrict__ outf,
    const float* __restrict__ bias, const float* __restrict__ resid)
{
    __shared__ u16 lsA[64 * 64];    // 8 KB
    __shared__ u16 lsB[128 * 64];   // 16 KB
    const int t = threadIdx.x;
    const int w = t >> 6, l = t & 63, lr = l & 15, quad = l >> 4;
    const int wr = w >> 1, wc = w & 1;
    // grouped XCD swizzle: nx=4 x-tiles, 2 y-tiles per group, x-major inside
    const int g = blockIdx.x;
    const int xcd = g & 7;
    const int q = g >> 3;
    const int grp = q >> 3, rem = q & 7;    // npg = 4*2 = 8
    const int tx = rem >> 1;
    const int ty = xcd * ypx + grp * 2 + (rem & 1);
    const int m0 = ty * 64, n0 = tx * 128;
    const int RW = wr * 32, CW = wc * 64;

    floatx4 acc[2][4];
    #pragma unroll
    for (int i = 0; i < 2; i++)
        #pragma unroll
        for (int j = 0; j < 4; j++) { floatx4 z = {0.f, 0.f, 0.f, 0.f}; acc[i][j] = z; }

    const int srow8 = l >> 3;
    const int scol = (((l & 7) - srow8) & 7) * 8;
    const u16* Ag = A  + (size_t)(m0 + w * 16 + srow8) * 512 + scol;   // wave w: A rows w*16..+15
    const u16* Bg = Bt + (size_t)(n0 + w * 32 + srow8) * 512 + scol;   // wave w: B rows w*32..+31
    u16* lAw = lsA + w * 1024;
    u16* lBw = lsB + w * 2048;

    for (int kk = 0; kk < 512; kk += 64) {
        __syncthreads();
        #pragma unroll
        for (int c = 0; c < 2; c++)
            g2lds16(Ag + (size_t)(c * 8) * 512 + kk, lAw + c * 512);
        #pragma unroll
        for (int c = 0; c < 4; c++)
            g2lds16(Bg + (size_t)(c * 8) * 512 + kk, lBw + c * 512);
        __syncthreads();
        #pragma unroll
        for (int ks = 0; ks < 2; ks++) {
            bf16x8 af[2], bfr[4];
            const int m = ((ks * 4 + quad + (lr & 7)) & 7) * 8;
            af[0] = *(const bf16x8*)(lsA + (RW + lr) * 64 + m);
            af[1] = *(const bf16x8*)(lsA + (RW + 16 + lr) * 64 + m);
            #pragma unroll
            for (int j = 0; j < 4; j++)
                bfr[j] = *(const bf16x8*)(lsB + (CW + j * 16 + lr) * 64 + m);
            #pragma unroll
            for (int i = 0; i < 2; i++)
                #pragma unroll
                for (int j = 0; j < 4; j++)
                    acc[i][j] = __builtin_amdgcn_mfma_f32_16x16x32_bf16(af[i], bfr[j], acc[i][j], 0, 0, 0);
        }
    }

    #pragma unroll
    for (int i = 0; i < 2; i++) {
        #pragma unroll
        for (int j = 0; j < 4; j++) {
            #pragma unroll
            for (int r = 0; r < 4; r++) {
                int row = m0 + RW + i * 16 + quad * 4 + r;
                int col = n0 + CW + j * 16 + lr;
                float v = acc[i][j][r];
                size_t idx = (size_t)row * ldc + col;
                if constexpr (EPI == 1) {
                    outf[idx] = resid[idx] + v;
                } else if constexpr (EPI == 2) {
                    v += bias[col];
                    v = 0.5f * v * (1.f + erff(v * 0.70710678118f));
                    outb[idx] = f2bf(v);
                } else {
                    outf[idx] = outf[idx] + v + bias[col];
                }
            }
        }
    }
}

// ---------------- KV partials via MFMA: per-wave private LDS tiles, no atomics ----------------
__global__ __launch_bounds__(256) void kv_reduce(
    const u16* __restrict__ qkv, float* __restrict__ Pkv, float* __restrict__ PKsum)
{
    const int bh = blockIdx.x;            // 0..127
    const int b = bh >> 4, h = bh & 15;
    const int chunk = blockIdx.y;         // 0..7
    const int t = threadIdx.x;
    const int w = t >> 6, l = t & 63, lr = l & 15, quad = l >> 4;
    __shared__ u16 lds[4 * 2 * 2048];     // [wave][buf][K 1024 | V 1024] = 32 KB

    const int sbase = chunk * 512 + w * 128;
    const u16* qbase = qkv + (size_t)b * SEQ * 1536 + 512 + h * HD;  // K part; V = +512

    const int sl0 = l >> 2;               // rows 0..15 (instr 0)
    const int sl1 = 16 + sl0;             // rows 16..31 (instr 1)
    const int cl  = l & 3;
    const int cg0 = (cl + (sl0 >> 3)) & 3;
    const int cg1 = (cl + (sl1 >> 3)) & 3;
    const int gof0 = sl0 * 1536 + cg0 * 8;
    const int gof1 = sl1 * 1536 + cg1 * 8;

    u16* myl = lds + w * 4096;

    const int offA0 = quad * 256 + ((((lr >> 3) + 0) - quad) & 3) * 8 + (lr & 7);  // d 0..15
    const int offA1 = quad * 256 + ((((lr >> 3) + 2) - quad) & 3) * 8 + (lr & 7);  // d 16..31

    floatx4 a00 = {0,0,0,0}, a01 = {0,0,0,0}, a10 = {0,0,0,0}, a11 = {0,0,0,0};
    float ks0 = 0.f, ks1 = 0.f;

    {
        const u16* gK = qbase + (size_t)sbase * 1536;
        g2lds16(gK + gof0,       myl);
        g2lds16(gK + gof1,       myl + 512);
        g2lds16(gK + 512 + gof0, myl + 1024);
        g2lds16(gK + 512 + gof1, myl + 1536);
    }
    #pragma unroll
    for (int st = 0; st < 4; st++) {
        if (st < 3) {                      // prefetch next buf before the drain
            const u16* gK = qbase + (size_t)(sbase + (st + 1) * 32) * 1536;
            u16* nl = myl + ((st + 1) & 1) * 2048;
            g2lds16(gK + gof0,       nl);
            g2lds16(gK + gof1,       nl + 512);
            g2lds16(gK + 512 + gof0, nl + 1024);
            g2lds16(gK + 512 + gof1, nl + 1536);
        }
        __syncthreads();                   // vmcnt(0) drain, compiler-safe fence
        const u16* lK = myl + (st & 1) * 2048;
        const u16* lV = lK + 1024;
        union { bf16x8 v; u16 u[8]; } fa0, fa1, fb0, fb1;
        #pragma unroll
        for (int j = 0; j < 8; j++) {
            fa0.u[j] = lK[offA0 + j * 32];
            fa1.u[j] = lK[offA1 + j * 32];
            fb0.u[j] = lV[offA0 + j * 32];
            fb1.u[j] = lV[offA1 + j * 32];
        }
        #pragma unroll
        for (int j = 0; j < 8; j++) { ks0 += bf2f(fa0.u[j]); ks1 += bf2f(fa1.u[j]); }
        a00 = __builtin_amdgcn_mfma_f32_16x16x32_bf16(fa0.v, fb0.v, a00, 0, 0, 0);
        a01 = __builtin_amdgcn_mfma_f32_16x16x32_bf16(fa0.v, fb1.v, a01, 0, 0, 0);
        a10 = __builtin_amdgcn_mfma_f32_16x16x32_bf16(fa1.v, fb0.v, a10, 0, 0, 0);
        a11 = __builtin_amdgcn_mfma_f32_16x16x32_bf16(fa1.v, fb1.v, a11, 0, 0, 0);
    }

    const int p = bh * 32 + chunk * 4 + w;
    float* dst = Pkv + (size_t)p * 1024;
    floatx4 accs[2][2] = {{a00, a01}, {a10, a11}};
    #pragma unroll
    for (int i = 0; i < 2; i++)
        #pragma unroll
        for (int j = 0; j < 2; j++)
            #pragma unroll
            for (int r = 0; r < 4; r++)
                dst[(i * 16 + quad * 4 + r) * 32 + j * 16 + lr] = accs[i][j][r];

    float k0 = ks0 + __shfl_xor(ks0, 16); k0 += __shfl_xor(k0, 32);
    float k1 = ks1 + __shfl_xor(ks1, 16); k1 += __shfl_xor(k1, 32);
    if (quad == 0) {
        PKsum[p * 32 + lr]      = k0;
        PKsum[p * 32 + 16 + lr] = k1;
    }
}

// ---------------- final reduce: 512 blocks (128 bh x 4 parts) ----------------
__global__ __launch_bounds__(256) void kv_final(
    const float* __restrict__ Pkv, const float* __restrict__ PKsum,
    float* __restrict__ KV, float* __restrict__ Ksum)
{
    const int blk = blockIdx.x;          // 512 = 128 bh x 4 parts
    const int bh = blk >> 2, part = blk & 3;
    const int t = threadIdx.x;
    const float* src = Pkv + (size_t)bh * 32 * 1024 + part * 256 + t;
    float a = 0.f;
    #pragma unroll 4
    for (int p = 0; p < 32; p++) a += src[(size_t)p * 1024];
    KV[(size_t)bh * 1024 + part * 256 + t] = a;
    if (part == 0 && t < 32) {
        float s = 0.f;
        for (int p = 0; p < 32; p++) s += PKsum[(bh * 32 + p) * 32 + t];
        Ksum[bh * 32 + t] = s;
    }
}

// ---------------- msg = (Q . KV) * SEQ / (Q . Ksum + eps) ----------------
__global__ __launch_bounds__(256) void msg_kernel(
    const u16* __restrict__ qkv, const float* __restrict__ KV,
    const float* __restrict__ Ksum, u16* __restrict__ msg)
{
    int blk = blockIdx.x;           // 1024 blocks
    int b = blk >> 7;
    int r0 = (blk & 127) * 32;
    int t = threadIdx.x;
    int h = t >> 4;
    int vd = (t & 15) * 2;
    float kv0[32], kv1[32], ksr[32];
    const float* kvh = KV + ((size_t)b * 16 + h) * 1024;
    const float* ksh = Ksum + (b * 16 + h) * 32;
    #pragma unroll
    for (int d = 0; d < 32; d++) {
        kv0[d] = kvh[d * 32 + vd];
        kv1[d] = kvh[d * 32 + vd + 1];
        ksr[d] = ksh[d];
    }
    __shared__ u16 Qs[4 * 512];
    const int srr = t >> 6;
    const int scc = (t & 63) * 8;
    for (int rg = 0; rg < 32; rg += 4) {
        size_t row = (size_t)b * SEQ + r0 + rg;
        uint4 qv = *(const uint4*)(qkv + (row + srr) * 1536 + scc);
        __syncthreads();
        *(uint4*)(Qs + srr * 512 + scc) = qv;
        __syncthreads();
        #pragma unroll
        for (int r2 = 0; r2 < 4; r2++) {
            const u16* qp = Qs + r2 * 512 + h * HD;
            float q[32];
            #pragma unroll
            for (int i0 = 0; i0 < 32; i0 += 8) {
                union { uint4 v; u16 u[8]; } uu;
                uu.v = *(const uint4*)(qp + i0);
                #pragma unroll
                for (int jq = 0; jq < 8; jq++) q[i0 + jq] = bf2f(uu.u[jq]);
            }
            float zdot = 0.f, m0 = 0.f, m1 = 0.f;
            #pragma unroll
            for (int d = 0; d < 32; d++) {
                float qd = q[d];
                zdot += qd * ksr[d];
                m0   += qd * kv0[d];
                m1   += qd * kv1[d];
            }
            float z = (float)SEQ / (zdot + 1e-6f);
            unsigned pack = (unsigned)f2bf(m0 * z) | ((unsigned)f2bf(m1 * z) << 16);
            *(unsigned*)(msg + (row + r2) * C + h * HD + vd) = pack;
        }
    }
}

extern "C" void kernel_launch(void* const* d_in, const int* in_sizes, int n_in,
                              void* d_out, int out_size, void* d_ws, size_t ws_size,
                              hipStream_t stream) {
    const float* x     = (const float*)d_in[0];
    const float* Wq    = (const float*)d_in[1];
    const float* Wk    = (const float*)d_in[2];
    const float* Wv    = (const float*)d_in[3];
    const float* Wm    = (const float*)d_in[4];
    const float* W1    = (const float*)d_in[5];
    const float* b1    = (const float*)d_in[6];
    const float* W2    = (const float*)d_in[7];
    const float* b2    = (const float*)d_in[8];
    const float* g_att = (const float*)d_in[9];
    const float* b_att = (const float*)d_in[10];
    const float* g_ffn = (const float*)d_in[11];
    const float* b_ffn = (const float*)d_in[12];
    float* out = (float*)d_out;

    // Workspace map (live ranges disjoint in time)
    char* ws = (char*)d_ws;
    u16*   Wqkvt = (u16*)(ws);                    // 1.5 MB
    u16*   Wmt   = (u16*)(ws + 0x180000);         // 0.5 MB
    u16*   W1t   = (u16*)(ws + 0x200000);         // 0.5 MB
    u16*   W2t   = (u16*)(ws + 0x280000);         // 0.5 MB
    float* KV    = (float*)(ws + 0x300000);       // 512 KB
    float* Ksum  = (float*)(ws + 0x380000);       // 16 KB
    u16*   hb    = (u16*)(ws + 0x400000);         // 32 MB (LN1 out; reused as msg)
    float* Pkv   = (float*)(ws + 0x400000);       // 16 MB, aliases hb (hb dead in step 4)
    float* PKsum = (float*)(ws + 0x1400000);      // 512 KB
    u16*   qkv   = (u16*)(ws + 0x2400000);        // 96 MB
    u16*   h2    = qkv;                           // 32 MB (qkv dead after step 5)
    u16*   f1    = (u16*)(ws + 0x4400000);        // 32 MB (in qkv tail, dead by step 8)

    // 1. weights -> bf16 transposed
    prep_weights<<<6 * 64, 256, 0, stream>>>(Wq, Wk, Wv, Wm, W1, W2,
                                             Wqkvt, Wmt, W1t, W2t);
    // 2. LN1
    ln_kernel<<<ROWS / 4, 256, 0, stream>>>(x, g_att, b_att, hb);
    // 3. qkv = h @ [Wq|Wk|Wv]  (proven gemm_tile + grouped swizzle)
    gemm_tile<0><<<3072, 256, 0, stream>>>(hb, Wqkvt, 512, 1536, 12, 32,
                                           qkv, nullptr, nullptr, nullptr);
    // 4. KV/Ksum: MFMA partials + final reduce (no atomics, no memset)
    kv_reduce<<<dim3(128, 8), 256, 0, stream>>>(qkv, Pkv, PKsum);
    kv_final<<<512, 256, 0, stream>>>(Pkv, PKsum, KV, Ksum);
    // 5. msg (overwrites hb region - Pkv already consumed)
    msg_kernel<<<1024, 256, 0, stream>>>(qkv, KV, Ksum, hb);
    // 6. x2 = x + msg @ Wm   (occupancy-optimized thin tile)
    gemm_thin<1><<<2048, 256, 0, stream>>>(hb, Wmt, 512, 64,
                                           nullptr, out, nullptr, x);
    // 7. LN2
    ln_kernel<<<ROWS / 4, 256, 0, stream>>>(out, g_ffn, b_ffn, h2);
    // 8. f1 = gelu(h2 @ W1 + b1)
    gemm_thin<2><<<2048, 256, 0, stream>>>(h2, W1t, 512, 64,
                                           f1, nullptr, b1, nullptr);
    // 9. out = x2 + f1 @ W2 + b2   (in place on d_out)
    gemm_thin<3><<<2048, 256, 0, stream>>>(f1, W2t, 512, 64,
                                           nullptr, out, b2, nullptr);
}